// Round 17
// baseline (629.456 us; speedup 1.0000x reference)
//
#include <hip/hip_runtime.h>

#define USH unsigned short

__device__ inline float bf2f(USH u){ return __uint_as_float(((unsigned)u)<<16); }
__device__ inline USH f2bf(float f){
  unsigned u = __float_as_uint(f);
  return (USH)((u + 0x7FFFu + ((u>>16)&1u))>>16);
}

typedef __attribute__((ext_vector_type(8))) short bf16x8;
typedef __attribute__((ext_vector_type(4))) float f32x4;

__device__ inline void gll16(const USH* g, USH* l){
  __builtin_amdgcn_global_load_lds((const __attribute__((address_space(1))) void*)g,
                                   (__attribute__((address_space(3))) void*)l, 16, 0, 0);
}

// ------------------------------------------------------------------
// im2col for conv1: x(512,28,28) f32 -> xcol[b*400 + y*20 + x][96] bf16
__global__ __launch_bounds__(256) void im2col_k(
    const float* __restrict__ x, USH* __restrict__ xcol)
{
  int b = blockIdx.x, t = threadIdx.x;
  __shared__ float xs[784];
  for (int i = t; i < 784; i += 256) xs[i] = x[b*784 + i];
  __syncthreads();
  USH* dst = xcol + (size_t)b*38400;
  for (int idx = t; idx < 38400; idx += 256) {
    int sp = idx / 96, k = idx - sp*96;
    int y = sp / 20, xx = sp - y*20;
    USH v = 0;
    if (k < 81) {
      int dy = k / 9, dx = k - dy*9;
      v = f2bf(xs[(y+dy)*28 + xx + dx]);
    }
    dst[idx] = v;
  }
}

// k1 (81,256) f32 -> k1T (256,96) bf16 zero-padded
__global__ __launch_bounds__(256) void tr_k1(const float* __restrict__ k1, USH* __restrict__ k1T)
{
  int n = threadIdx.x;
  for (int k = 0; k < 96; ++k)
    k1T[n*96 + k] = (k < 81) ? f2bf(k1[k*256 + n]) : (USH)0;
}

// ------------------------------------------------------------------
// conv1 as GEMM: C[204800 x 256] = xcol @ k1T^T, +bias, relu -> h bf16. No LDS.
__global__ __launch_bounds__(256) void gemm1(
    const USH* __restrict__ xcol, const USH* __restrict__ k1T,
    const float* __restrict__ b1, USH* __restrict__ h)
{
  int t = threadIdx.x;
  int m0 = blockIdx.x * 64;
  int lane = t & 63, wave = t >> 6;
  int wn = wave * 64;
  int fr = lane & 15, fq = lane >> 4;

  f32x4 acc[4][4];
#pragma unroll
  for (int i = 0; i < 4; ++i)
#pragma unroll
    for (int j = 0; j < 4; ++j)
#pragma unroll
      for (int r = 0; r < 4; ++r) acc[i][j][r] = 0.f;

#pragma unroll
  for (int kt = 0; kt < 3; ++kt) {
    int kc = kt*32 + fq*8;
    bf16x8 af[4], bg[4];
#pragma unroll
    for (int mf = 0; mf < 4; ++mf)
      af[mf] = *(const bf16x8*)&xcol[(size_t)(m0 + mf*16 + fr)*96 + kc];
#pragma unroll
    for (int nf = 0; nf < 4; ++nf)
      bg[nf] = *(const bf16x8*)&k1T[(size_t)(wn + nf*16 + fr)*96 + kc];
#pragma unroll
    for (int mf = 0; mf < 4; ++mf)
#pragma unroll
      for (int nf = 0; nf < 4; ++nf)
        acc[mf][nf] = __builtin_amdgcn_mfma_f32_16x16x32_bf16(af[mf], bg[nf], acc[mf][nf], 0,0,0);
  }

#pragma unroll
  for (int mf = 0; mf < 4; ++mf)
#pragma unroll
    for (int nf = 0; nf < 4; ++nf) {
      int n = wn + nf*16 + fr;
      float bias = b1[n];
#pragma unroll
      for (int r = 0; r < 4; ++r) {
        int m = m0 + mf*16 + fq*4 + r;
        float v = acc[mf][nf][r] + bias;
        h[(size_t)m*256 + n] = f2bf(v > 0.f ? v : 0.f);
      }
    }
}

// ------------------------------------------------------------------
// k2 (20736,256) f32 -> k2T (256,20736) bf16
__global__ __launch_bounds__(256) void tr_k2(const float* __restrict__ k2, USH* __restrict__ k2T)
{
  __shared__ float tile[32][33];
  int kb = blockIdx.x*32, nb = blockIdx.y*32;
  int tx = threadIdx.x & 31, ty = threadIdx.x >> 5;
#pragma unroll
  for (int r = 0; r < 4; ++r) {
    int k = kb + ty + r*8;
    tile[ty + r*8][tx] = k2[(size_t)k*256 + nb + tx];
  }
  __syncthreads();
#pragma unroll
  for (int r = 0; r < 4; ++r) {
    int n = nb + ty + r*8;
    k2T[(size_t)n*20736 + kb + tx] = f2bf(tile[tx][ty + r*8]);
  }
}

// ------------------------------------------------------------------
// conv2 implicit GEMM: bf16 MFMA 16x16x32, BM=128 BN=64 BK=64, 4 waves,
// 2-buffer LDS + XOR swizzle, split-K x4, XCD-aware 1D grid (r15-proven).
__global__ __launch_bounds__(256) void conv2_mfma(
    const USH* __restrict__ h, const USH* __restrict__ k2T,
    float* __restrict__ up)
{
  __shared__ __align__(16) USH Asm[2][128*64];
  __shared__ __align__(16) USH Bsm[2][64*64];
  int t = threadIdx.x;
  int flat = blockIdx.x;
  int xcd  = flat & 7;
  int slot = flat >> 3;
  int nb   = slot & 3;
  int rest = slot >> 2;
  int mb_l = rest % 18;
  int ksl  = rest / 18;
  int mb   = xcd*18 + mb_l;

  int sg = (((t&7) ^ ((t>>3)&7)) << 3);

  int arow_off[4];
#pragma unroll
  for (int i = 0; i < 4; ++i) {
    int row = (t>>3) + i*32;
    int m = mb*128 + row;
    int bb = m/36, r = m - bb*36;
    int oy = r/6, ox = r - oy*6;
    arow_off[i] = bb*102400 + oy*10240 + ox*512 + sg;
  }
  int brow_off[2];
#pragma unroll
  for (int i = 0; i < 2; ++i) {
    int nl = (t>>3) + i*32;
    brow_off[i] = (nb*64 + nl)*20736 + sg;
  }

  int lane = t & 63;
  int wave = t >> 6;
  int wm = (wave>>1)*64, wn = (wave&1)*32;
  int fr = lane & 15, fq = lane >> 4;

  f32x4 acc[4][2];
#pragma unroll
  for (int i = 0; i < 4; ++i)
#pragma unroll
    for (int j = 0; j < 2; ++j)
#pragma unroll
      for (int r = 0; r < 4; ++r) acc[i][j][r] = 0.f;

  int rg0 = (((0*4 + fq) ^ (fr&7)) << 3);
  int rg1 = (((1*4 + fq) ^ (fr&7)) << 3);

#define STAGE(buf, kt) do {                                            \
    int j_ = (kt) >> 2;                                                \
    int cin0_ = ((kt) & 3) << 6;                                       \
    int dy_ = j_/9, dx_ = j_ - dy_*9;                                  \
    int koff_ = (dy_*20 + dx_)*256 + cin0_;                            \
    USH* Ad_ = &Asm[buf][(t>>6)*512];                                  \
    USH* Bd_ = &Bsm[buf][(t>>6)*512];                                  \
    _Pragma("unroll")                                                  \
    for (int i_ = 0; i_ < 4; ++i_) gll16(h + arow_off[i_] + koff_, Ad_ + i_*2048); \
    _Pragma("unroll")                                                  \
    for (int i_ = 0; i_ < 2; ++i_) gll16(k2T + brow_off[i_] + (kt)*64, Bd_ + i_*2048); \
  } while(0)

  const int k0 = ksl*81, kend = k0 + 81;
  STAGE(0, k0);
  __syncthreads();

  int cur = 0;
  for (int kt = k0; kt < kend; ++kt) {
    if (kt + 1 < kend) STAGE(cur^1, kt+1);

    bf16x8 af[4][2], bg[2][2];
#pragma unroll
    for (int mf = 0; mf < 4; ++mf) {
      af[mf][0] = *(const bf16x8*)&Asm[cur][(wm + mf*16 + fr)*64 + rg0];
      af[mf][1] = *(const bf16x8*)&Asm[cur][(wm + mf*16 + fr)*64 + rg1];
    }
#pragma unroll
    for (int nf = 0; nf < 2; ++nf) {
      bg[nf][0] = *(const bf16x8*)&Bsm[cur][(wn + nf*16 + fr)*64 + rg0];
      bg[nf][1] = *(const bf16x8*)&Bsm[cur][(wn + nf*16 + fr)*64 + rg1];
    }
#pragma unroll
    for (int mf = 0; mf < 4; ++mf)
#pragma unroll
      for (int nf = 0; nf < 2; ++nf) {
        acc[mf][nf] = __builtin_amdgcn_mfma_f32_16x16x32_bf16(af[mf][0], bg[nf][0], acc[mf][nf], 0,0,0);
        acc[mf][nf] = __builtin_amdgcn_mfma_f32_16x16x32_bf16(af[mf][1], bg[nf][1], acc[mf][nf], 0,0,0);
      }
    __syncthreads();
    cur ^= 1;
  }
#undef STAGE

  float* dst = up + (size_t)ksl*4718592;
#pragma unroll
  for (int mf = 0; mf < 4; ++mf)
#pragma unroll
    for (int nf = 0; nf < 2; ++nf) {
      int n = nb*64 + wn + nf*16 + fr;
#pragma unroll
      for (int r = 0; r < 4; ++r) {
        int m = mb*128 + wm + mf*16 + fq*4 + r;
        dst[(size_t)m*256 + n] = acc[mf][nf][r];
      }
    }
}

// ------------------------------------------------------------------
// u = up[0]+up[1]+up[2]+up[3] + bias  (f32x4 over 18432x256)
__global__ __launch_bounds__(256) void reduce_u(
    const float* __restrict__ up, const float* __restrict__ b2, float* __restrict__ u)
{
  int i = blockIdx.x*256 + threadIdx.x;
  f32x4 a = *(const f32x4*)&up[(size_t)i*4];
  f32x4 b = *(const f32x4*)&up[4718592ull + (size_t)i*4];
  f32x4 c = *(const f32x4*)&up[9437184ull + (size_t)i*4];
  f32x4 d = *(const f32x4*)&up[14155776ull + (size_t)i*4];
  int n0 = (i*4) & 255;
  f32x4 o;
#pragma unroll
  for (int j = 0; j < 4; ++j) o[j] = (a[j] + b[j]) + (c[j] + d[j]) + b2[n0 + j];
  *(f32x4*)&u[(size_t)i*4] = o;
}

// ------------------------------------------------------------------
// Wsum[n*8+p][sd] = w[n, sd>>4, sd&15, p]   (9216 x 160 f32)
__global__ __launch_bounds__(192) void wsum_tr(const float* __restrict__ w,
    float* __restrict__ Ws)
{
  int n = blockIdx.x, t = threadIdx.x;
  __shared__ float wn[1280];
  for (int i = t; i < 1280; i += 192) wn[i] = w[n*1280 + i];
  __syncthreads();
  if (t < 160) {
#pragma unroll
    for (int p = 0; p < 8; ++p)
      Ws[((size_t)n*8 + p)*160 + t] = wn[(t>>4)*128 + (t&15)*8 + p];
  }
}

// ------------------------------------------------------------------
// s1 partials: part[ks][b][160] = u[b, k0:k0+288] @ Ws[k0:k0+288, :]
__global__ __launch_bounds__(192) void p1gemm(const float* __restrict__ u,
    const float* __restrict__ Ws, float* __restrict__ part)
{
  int b0 = blockIdx.x*32, k0 = blockIdx.y*288;
  int t = threadIdx.x;
  __shared__ float usm[288*36];
  for (int i = t; i < 288*32; i += 192) {
    int bl = i/288, kk = i - bl*288;
    usm[kk*36 + bl] = u[(size_t)(b0+bl)*9216 + k0 + kk];
  }
  __syncthreads();
  if (t < 160) {
    const float* wp = Ws + (size_t)k0*160 + t;
#pragma unroll 1
    for (int half = 0; half < 2; ++half) {
      float acc[16];
#pragma unroll
      for (int i = 0; i < 16; ++i) acc[i] = 0.f;
      for (int kk = 0; kk < 288; ++kk) {
        float wv = wp[(size_t)kk*160];
        const f32x4* ub = (const f32x4*)&usm[kk*36 + half*16];
        f32x4 u0 = ub[0], u1 = ub[1], u2 = ub[2], u3 = ub[3];
#pragma unroll
        for (int i = 0; i < 4; ++i) {
          acc[i]    += u0[i]*wv;
          acc[4+i]  += u1[i]*wv;
          acc[8+i]  += u2[i]*wv;
          acc[12+i] += u3[i]*wv;
        }
      }
      float* pp = &part[((size_t)blockIdx.y*512 + b0 + half*16)*160 + t];
#pragma unroll
      for (int i = 0; i < 16; ++i) pp[(size_t)i*160] = acc[i];
    }
  }
}

// ------------------------------------------------------------------
// v1 = squash(0.1 * sum_ks part[ks][b][:])
__global__ __launch_bounds__(192) void squash1(const float* __restrict__ part,
    float* __restrict__ vout)
{
  int b = blockIdx.x, t = threadIdx.x;
  if (t < 160) {
    float sv = 0.f;
    for (int ks = 0; ks < 32; ++ks) sv += part[((size_t)ks*512 + b)*160 + t];
    sv *= 0.1f;
    float n2 = sv*sv;
    n2 += __shfl_xor(n2, 1, 16);
    n2 += __shfl_xor(n2, 2, 16);
    n2 += __shfl_xor(n2, 4, 16);
    n2 += __shfl_xor(n2, 8, 16);
    float nrm = sqrtf(n2);
    float o = (n2/(1.f + n2)) * sv / (nrm + 1e-7f);
    vout[b*160 + t] = o;
  }
}

// ------------------------------------------------------------------
// u_hat -> uh[n][b][160] bf16 (n-major: stores fully coalesced).
__global__ __launch_bounds__(256) void uhat_kernel(
    const float* __restrict__ u, const float* __restrict__ w, USH* __restrict__ uh)
{
  int n = blockIdx.x, b0 = blockIdx.y*64;
  int t = threadIdx.x;
  __shared__ float wsm[20*65];
  __shared__ float usm[512];
  for (int i = t; i < 1280; i += 256) wsm[(i>>6)*65 + (i&63)] = w[n*1280 + i];
  for (int i = t; i < 512; i += 256) {
    int bl = i>>3, p = i&7;
    usm[i] = u[(size_t)(b0+bl)*9216 + n*8 + p];
  }
  __syncthreads();
  USH* dst = uh + ((size_t)n*512 + b0)*160;
  for (int v = t; v < 1280; v += 256) {
    int bl = v/20, oct = v - bl*20;
    const float* upt = &usm[bl*8];
    bf16x8 pk;
#pragma unroll
    for (int j = 0; j < 8; ++j) {
      const float* wp = &wsm[oct*65 + j*8];
      float a = 0.f;
#pragma unroll
      for (int p = 0; p < 8; ++p) a += wp[p]*upt[p];
      pk[j] = (short)f2bf(a);
    }
    *(bf16x8*)&dst[(size_t)v*8] = pk;
  }
}

// ------------------------------------------------------------------
// Routing pass partial, coalesced-b mapping: block = (16 b, 16 n),
// grid (32 bc, 72 nc) = 2304 blocks (~9/CU). Thread (bL, s): per n the
// block's active lanes read uh[n][b0..b15][0..160] = ONE contiguous 5KB
// span; each thread owns (b,s,d) outright -> NO LDS, NO barrier, no
// reduce. Softmax = width-16 shfl (s = low 4 lane bits). 2-deep n-prefetch.
// No L buffer: pass2 vin=v1; pass3 vin=v1+v2 (logits3 = uh.(v1+v2)).
__global__ __launch_bounds__(256) void route_part(
    const USH* __restrict__ uh, const float* __restrict__ vin,
    float* __restrict__ partR)
{
  int bc = blockIdx.x, nc = blockIdx.y;
  int b0 = bc*16, n0 = nc*16;
  int t = threadIdx.x;
  int bL = t >> 4, s = t & 15;
  bool act = s < 10;
  int b = b0 + bL;

  float vr[16];
#pragma unroll
  for (int d = 0; d < 16; ++d) vr[d] = 0.f;
  if (act) {
    const float* vp = vin + (size_t)b*160 + s*16;
#pragma unroll
    for (int d = 0; d < 16; ++d) vr[d] = vp[d];
  }
  float acc[16];
#pragma unroll
  for (int d = 0; d < 16; ++d) acc[d] = 0.f;

  const size_t nstride = (size_t)512*160;
  const USH* base = uh + ((size_t)n0*512 + b)*160 + s*16;

  bf16x8 c0{}, c1{};
  if (act) { c0 = *(const bf16x8*)base; c1 = *(const bf16x8*)(base + 8); }

  for (int ni = 0; ni < 16; ++ni) {
    bf16x8 f0 = c0, f1 = c1;
    if (ni + 1 < 16 && act) {
      const USH* p = base + (size_t)(ni+1)*nstride;
      f0 = *(const bf16x8*)p;
      f1 = *(const bf16x8*)(p + 8);
    }
    float uv[16];
    if (act) {
#pragma unroll
      for (int d = 0; d < 8; ++d) { uv[d] = bf2f((USH)c0[d]); uv[8+d] = bf2f((USH)c1[d]); }
    } else {
#pragma unroll
      for (int d = 0; d < 16; ++d) uv[d] = 0.f;
    }
    c0 = f0; c1 = f1;

    float dot = 0.f;
#pragma unroll
    for (int d = 0; d < 16; ++d) dot += uv[d]*vr[d];
    float lg = act ? dot : -1e30f;
    float mx = lg;
    mx = fmaxf(mx, __shfl_xor(mx, 1, 16));
    mx = fmaxf(mx, __shfl_xor(mx, 2, 16));
    mx = fmaxf(mx, __shfl_xor(mx, 4, 16));
    mx = fmaxf(mx, __shfl_xor(mx, 8, 16));
    float e = __expf(lg - mx);
    float sum = e;
    sum += __shfl_xor(sum, 1, 16);
    sum += __shfl_xor(sum, 2, 16);
    sum += __shfl_xor(sum, 4, 16);
    sum += __shfl_xor(sum, 8, 16);
    float c = e / sum;
#pragma unroll
    for (int d = 0; d < 16; ++d) acc[d] += c*uv[d];
  }

  if (act) {
    float* pp = &partR[((size_t)nc*512 + b)*160 + s*16];
#pragma unroll
    for (int q = 0; q < 4; ++q) {
      f32x4 o;
#pragma unroll
      for (int j = 0; j < 4; ++j) o[j] = acc[q*4 + j];
      *(f32x4*)(pp + q*4) = o;
    }
  }
}

// ------------------------------------------------------------------
// squash over 72 n-chunk partials.
// PASS2: vout=v2, vext=vprev+v2 (vsum). PASS3: vout=v3, vext=out.
template<int PASS>
__global__ __launch_bounds__(192) void squash_part(const float* __restrict__ partR,
    const float* __restrict__ vprev, float* __restrict__ vout, float* __restrict__ vext)
{
  int b = blockIdx.x, t = threadIdx.x;
  if (t < 160) {
    float sv = 0.f;
    for (int nc = 0; nc < 72; ++nc) sv += partR[((size_t)nc*512 + b)*160 + t];
    float n2 = sv*sv;
    n2 += __shfl_xor(n2, 1, 16);
    n2 += __shfl_xor(n2, 2, 16);
    n2 += __shfl_xor(n2, 4, 16);
    n2 += __shfl_xor(n2, 8, 16);
    float nrm = sqrtf(n2);
    float o = (n2/(1.f + n2)) * sv / (nrm + 1e-7f);
    vout[b*160 + t] = o;
    if (PASS == 2) vext[b*160 + t] = vprev[b*160 + t] + o;   // vsum = v1 + v2
    if (PASS == 3) vext[b*160 + t] = o;                       // out[0:81920] = v
  }
}

// ------------------------------------------------------------------
// decoder
__global__ __launch_bounds__(512) void d1_kernel(const float* __restrict__ v3,
    const int* __restrict__ labels, const float* __restrict__ w,
    const float* __restrict__ bias, float* __restrict__ r1)
{
  int b = blockIdx.x; int j = threadIdx.x;
  int lb = labels[b];
  float acc = bias[j];
#pragma unroll
  for (int d = 0; d < 16; ++d)
    acc += v3[b*160 + lb*16 + d] * w[(lb*16 + d)*512 + j];
  r1[(size_t)b*512 + j] = acc > 0.f ? acc : 0.f;
}

__global__ __launch_bounds__(256) void d2_kernel(const float* __restrict__ a,
    const float* __restrict__ w, const float* __restrict__ bias, float* __restrict__ o)
{
  int j = blockIdx.x*256 + threadIdx.x;
  int b0 = blockIdx.y*4;
  __shared__ float as[4*512];
  for (int i = threadIdx.x; i < 4*512; i += 256) as[i] = a[(size_t)(b0 + (i>>9))*512 + (i&511)];
  __syncthreads();
  float acc[4];
  float bs = bias[j];
#pragma unroll
  for (int i = 0; i < 4; ++i) acc[i] = bs;
  for (int k = 0; k < 512; ++k) {
    float wv = w[(size_t)k*1024 + j];
#pragma unroll
    for (int i = 0; i < 4; ++i) acc[i] += as[i*512 + k]*wv;
  }
#pragma unroll
  for (int i = 0; i < 4; ++i)
    o[(size_t)(b0+i)*1024 + j] = acc[i] > 0.f ? acc[i] : 0.f;
}

__global__ __launch_bounds__(256) void d3_kernel(const float* __restrict__ a,
    const float* __restrict__ w, const float* __restrict__ bias, float* __restrict__ o)
{
  int j = blockIdx.x*256 + threadIdx.x;
  int b0 = blockIdx.y*4;
  __shared__ float as[4*1024];
  for (int i = threadIdx.x; i < 4*1024; i += 256) as[i] = a[(size_t)(b0 + (i>>10))*1024 + (i&1023)];
  __syncthreads();
  if (j < 784) {
    float acc[4];
    float bs = bias[j];
#pragma unroll
    for (int i = 0; i < 4; ++i) acc[i] = bs;
    for (int k = 0; k < 1024; ++k) {
      float wv = w[(size_t)k*784 + j];
#pragma unroll
      for (int i = 0; i < 4; ++i) acc[i] += as[i*1024 + k]*wv;
    }
#pragma unroll
    for (int i = 0; i < 4; ++i)
      o[(size_t)(b0+i)*784 + j] = 1.f/(1.f + __expf(-acc[i]));
  }
}

// ------------------------------------------------------------------
extern "C" void kernel_launch(void* const* d_in, const int* in_sizes, int n_in,
                              void* d_out, int out_size, void* d_ws, size_t ws_size,
                              hipStream_t stream)
{
  const float* x   = (const float*)d_in[0];
  const int*   lab = (const int*)  d_in[1];
  const float* k1  = (const float*)d_in[2];
  const float* b1  = (const float*)d_in[3];
  const float* k2  = (const float*)d_in[4];
  const float* b2  = (const float*)d_in[5];
  const float* w   = (const float*)d_in[6];
  const float* d1w = (const float*)d_in[7];
  const float* d1b = (const float*)d_in[8];
  const float* d2w = (const float*)d_in[9];
  const float* d2b = (const float*)d_in[10];
  const float* d3w = (const float*)d_in[11];
  const float* d3b = (const float*)d_in[12];
  float* out = (float*)d_out;

  char* ws = (char*)d_ws;
  // layout (bytes) -- liveness audited (r16 bug: partR had overlaid live uh):
  //   uh    [0, 188743680)          bf16 [1152][512][160] (n-major); LIVE from
  //                                 uhat until last route_part.
  //   h     overlays [0, 104857600)   dead after conv2 (before uhat writes uh)
  //   up    [104857600, 180355072)    dead after reduce_u (before uhat)
  //   xcol  [142606336, 181927936)    dead after gemm1 (before conv2 writes up)
  //   u     [188743680, 207618048)    live conv2->uhat/p1gemm
  //   Wsum  [207618048, 213516288)    in dead-k2T region; dead after p1gemm
  //   k2T   [207618048, 218234880)    dead after conv2 (Wsum overlays then)
  //   part  [218234880, 228720640)    p1 partials; dead after squash1
  //   partR [218234880, 241827840)    route partials (old L region, disjoint
  //                                   from uh); live only route phase
  //   k1T   [241827840, 241926144)
  //   v/r   beyond 242155520
  USH*   uh    = (USH*)(ws + 0);
  USH*   h     = (USH*)(ws + 0);
  float* up    = (float*)(ws + 104857600ull);
  USH*   xcol  = (USH*)(ws + 142606336ull);
  float* u     = (float*)(ws + 188743680ull);
  USH*   k2T   = (USH*)(ws + 207618048ull);
  float* Wsum  = (float*)(ws + 207618048ull);
  float* part  = (float*)(ws + 218234880ull);
  float* partR = (float*)(ws + 218234880ull);
  USH*   k1T   = (USH*)(ws + 241827840ull);
  float* v1    = (float*)(ws + 242155520ull);
  float* v2    = (float*)(ws + 242483200ull);
  float* v3    = (float*)(ws + 242810880ull);
  float* vsum  = (float*)(ws + 243138560ull);
  float* r1    = (float*)(ws + 243466240ull);
  float* r2    = (float*)(ws + 244514816ull);

  im2col_k<<<512, 256, 0, stream>>>(x, xcol);
  tr_k1<<<1, 256, 0, stream>>>(k1, k1T);
  gemm1<<<3200, 256, 0, stream>>>(xcol, k1T, b1, h);

  tr_k2<<<dim3(648,8), 256, 0, stream>>>(k2, k2T);
  conv2_mfma<<<2304, 256, 0, stream>>>(h, k2T, up);
  reduce_u<<<4608, 256, 0, stream>>>(up, b2, u);

  wsum_tr<<<1152, 192, 0, stream>>>(w, Wsum);
  p1gemm<<<dim3(16,32), 192, 0, stream>>>(u, Wsum, part);
  squash1<<<512, 192, 0, stream>>>(part, v1);

  uhat_kernel<<<dim3(1152,8), 256, 0, stream>>>(u, w, uh);

  route_part<<<dim3(32,72), 256, 0, stream>>>(uh, v1, partR);
  squash_part<2><<<512, 192, 0, stream>>>(partR, v1, v2, vsum);
  route_part<<<dim3(32,72), 256, 0, stream>>>(uh, vsum, partR);
  squash_part<3><<<512, 192, 0, stream>>>(partR, nullptr, v3, out);

  d1_kernel<<<512, 512, 0, stream>>>(v3, lab, d1w, d1b, r1);
  d2_kernel<<<dim3(4,128), 256, 0, stream>>>(r1, d2w, d2b, r2);
  d3_kernel<<<dim3(4,128), 256, 0, stream>>>(r2, d3w, d3b, out + 81920);
}

// Round 18
// 602.216 us; speedup vs baseline: 1.0452x; 1.0452x over previous
//
#include <hip/hip_runtime.h>

#define USH unsigned short

__device__ inline float bf2f(USH u){ return __uint_as_float(((unsigned)u)<<16); }
__device__ inline USH f2bf(float f){
  unsigned u = __float_as_uint(f);
  return (USH)((u + 0x7FFFu + ((u>>16)&1u))>>16);
}

typedef __attribute__((ext_vector_type(8))) short bf16x8;
typedef __attribute__((ext_vector_type(4))) float f32x4;

__device__ inline void gll16(const USH* g, USH* l){
  __builtin_amdgcn_global_load_lds((const __attribute__((address_space(1))) void*)g,
                                   (__attribute__((address_space(3))) void*)l, 16, 0, 0);
}

// ------------------------------------------------------------------
// im2col for conv1: x(512,28,28) f32 -> xcol[b*400 + y*20 + x][96] bf16
__global__ __launch_bounds__(256) void im2col_k(
    const float* __restrict__ x, USH* __restrict__ xcol)
{
  int b = blockIdx.x, t = threadIdx.x;
  __shared__ float xs[784];
  for (int i = t; i < 784; i += 256) xs[i] = x[b*784 + i];
  __syncthreads();
  USH* dst = xcol + (size_t)b*38400;
  for (int idx = t; idx < 38400; idx += 256) {
    int sp = idx / 96, k = idx - sp*96;
    int y = sp / 20, xx = sp - y*20;
    USH v = 0;
    if (k < 81) {
      int dy = k / 9, dx = k - dy*9;
      v = f2bf(xs[(y+dy)*28 + xx + dx]);
    }
    dst[idx] = v;
  }
}

// k1 (81,256) f32 -> k1T (256,96) bf16 zero-padded
__global__ __launch_bounds__(256) void tr_k1(const float* __restrict__ k1, USH* __restrict__ k1T)
{
  int n = threadIdx.x;
  for (int k = 0; k < 96; ++k)
    k1T[n*96 + k] = (k < 81) ? f2bf(k1[k*256 + n]) : (USH)0;
}

// ------------------------------------------------------------------
// conv1 as GEMM: C[204800 x 256] = xcol @ k1T^T, +bias, relu -> h bf16. No LDS.
__global__ __launch_bounds__(256) void gemm1(
    const USH* __restrict__ xcol, const USH* __restrict__ k1T,
    const float* __restrict__ b1, USH* __restrict__ h)
{
  int t = threadIdx.x;
  int m0 = blockIdx.x * 64;
  int lane = t & 63, wave = t >> 6;
  int wn = wave * 64;
  int fr = lane & 15, fq = lane >> 4;

  f32x4 acc[4][4];
#pragma unroll
  for (int i = 0; i < 4; ++i)
#pragma unroll
    for (int j = 0; j < 4; ++j)
#pragma unroll
      for (int r = 0; r < 4; ++r) acc[i][j][r] = 0.f;

#pragma unroll
  for (int kt = 0; kt < 3; ++kt) {
    int kc = kt*32 + fq*8;
    bf16x8 af[4], bg[4];
#pragma unroll
    for (int mf = 0; mf < 4; ++mf)
      af[mf] = *(const bf16x8*)&xcol[(size_t)(m0 + mf*16 + fr)*96 + kc];
#pragma unroll
    for (int nf = 0; nf < 4; ++nf)
      bg[nf] = *(const bf16x8*)&k1T[(size_t)(wn + nf*16 + fr)*96 + kc];
#pragma unroll
    for (int mf = 0; mf < 4; ++mf)
#pragma unroll
      for (int nf = 0; nf < 4; ++nf)
        acc[mf][nf] = __builtin_amdgcn_mfma_f32_16x16x32_bf16(af[mf], bg[nf], acc[mf][nf], 0,0,0);
  }

#pragma unroll
  for (int mf = 0; mf < 4; ++mf)
#pragma unroll
    for (int nf = 0; nf < 4; ++nf) {
      int n = wn + nf*16 + fr;
      float bias = b1[n];
#pragma unroll
      for (int r = 0; r < 4; ++r) {
        int m = m0 + mf*16 + fq*4 + r;
        float v = acc[mf][nf][r] + bias;
        h[(size_t)m*256 + n] = f2bf(v > 0.f ? v : 0.f);
      }
    }
}

// ------------------------------------------------------------------
// k2 (20736,256) f32 -> k2T (256,20736) bf16
__global__ __launch_bounds__(256) void tr_k2(const float* __restrict__ k2, USH* __restrict__ k2T)
{
  __shared__ float tile[32][33];
  int kb = blockIdx.x*32, nb = blockIdx.y*32;
  int tx = threadIdx.x & 31, ty = threadIdx.x >> 5;
#pragma unroll
  for (int r = 0; r < 4; ++r) {
    int k = kb + ty + r*8;
    tile[ty + r*8][tx] = k2[(size_t)k*256 + nb + tx];
  }
  __syncthreads();
#pragma unroll
  for (int r = 0; r < 4; ++r) {
    int n = nb + ty + r*8;
    k2T[(size_t)n*20736 + kb + tx] = f2bf(tile[tx][ty + r*8]);
  }
}

// ------------------------------------------------------------------
// conv2 implicit GEMM: bf16 MFMA 16x16x32, BM=128 BN=64 BK=64, 4 waves,
// 2-buffer LDS + XOR swizzle, split-K x4, XCD-aware 1D grid (r15-proven).
__global__ __launch_bounds__(256) void conv2_mfma(
    const USH* __restrict__ h, const USH* __restrict__ k2T,
    float* __restrict__ up)
{
  __shared__ __align__(16) USH Asm[2][128*64];
  __shared__ __align__(16) USH Bsm[2][64*64];
  int t = threadIdx.x;
  int flat = blockIdx.x;
  int xcd  = flat & 7;
  int slot = flat >> 3;
  int nb   = slot & 3;
  int rest = slot >> 2;
  int mb_l = rest % 18;
  int ksl  = rest / 18;
  int mb   = xcd*18 + mb_l;

  int sg = (((t&7) ^ ((t>>3)&7)) << 3);

  int arow_off[4];
#pragma unroll
  for (int i = 0; i < 4; ++i) {
    int row = (t>>3) + i*32;
    int m = mb*128 + row;
    int bb = m/36, r = m - bb*36;
    int oy = r/6, ox = r - oy*6;
    arow_off[i] = bb*102400 + oy*10240 + ox*512 + sg;
  }
  int brow_off[2];
#pragma unroll
  for (int i = 0; i < 2; ++i) {
    int nl = (t>>3) + i*32;
    brow_off[i] = (nb*64 + nl)*20736 + sg;
  }

  int lane = t & 63;
  int wave = t >> 6;
  int wm = (wave>>1)*64, wn = (wave&1)*32;
  int fr = lane & 15, fq = lane >> 4;

  f32x4 acc[4][2];
#pragma unroll
  for (int i = 0; i < 4; ++i)
#pragma unroll
    for (int j = 0; j < 2; ++j)
#pragma unroll
      for (int r = 0; r < 4; ++r) acc[i][j][r] = 0.f;

  int rg0 = (((0*4 + fq) ^ (fr&7)) << 3);
  int rg1 = (((1*4 + fq) ^ (fr&7)) << 3);

#define STAGE(buf, kt) do {                                            \
    int j_ = (kt) >> 2;                                                \
    int cin0_ = ((kt) & 3) << 6;                                       \
    int dy_ = j_/9, dx_ = j_ - dy_*9;                                  \
    int koff_ = (dy_*20 + dx_)*256 + cin0_;                            \
    USH* Ad_ = &Asm[buf][(t>>6)*512];                                  \
    USH* Bd_ = &Bsm[buf][(t>>6)*512];                                  \
    _Pragma("unroll")                                                  \
    for (int i_ = 0; i_ < 4; ++i_) gll16(h + arow_off[i_] + koff_, Ad_ + i_*2048); \
    _Pragma("unroll")                                                  \
    for (int i_ = 0; i_ < 2; ++i_) gll16(k2T + brow_off[i_] + (kt)*64, Bd_ + i_*2048); \
  } while(0)

  const int k0 = ksl*81, kend = k0 + 81;
  STAGE(0, k0);
  __syncthreads();

  int cur = 0;
  for (int kt = k0; kt < kend; ++kt) {
    if (kt + 1 < kend) STAGE(cur^1, kt+1);

    bf16x8 af[4][2], bg[2][2];
#pragma unroll
    for (int mf = 0; mf < 4; ++mf) {
      af[mf][0] = *(const bf16x8*)&Asm[cur][(wm + mf*16 + fr)*64 + rg0];
      af[mf][1] = *(const bf16x8*)&Asm[cur][(wm + mf*16 + fr)*64 + rg1];
    }
#pragma unroll
    for (int nf = 0; nf < 2; ++nf) {
      bg[nf][0] = *(const bf16x8*)&Bsm[cur][(wn + nf*16 + fr)*64 + rg0];
      bg[nf][1] = *(const bf16x8*)&Bsm[cur][(wn + nf*16 + fr)*64 + rg1];
    }
#pragma unroll
    for (int mf = 0; mf < 4; ++mf)
#pragma unroll
      for (int nf = 0; nf < 2; ++nf) {
        acc[mf][nf] = __builtin_amdgcn_mfma_f32_16x16x32_bf16(af[mf][0], bg[nf][0], acc[mf][nf], 0,0,0);
        acc[mf][nf] = __builtin_amdgcn_mfma_f32_16x16x32_bf16(af[mf][1], bg[nf][1], acc[mf][nf], 0,0,0);
      }
    __syncthreads();
    cur ^= 1;
  }
#undef STAGE

  float* dst = up + (size_t)ksl*4718592;
#pragma unroll
  for (int mf = 0; mf < 4; ++mf)
#pragma unroll
    for (int nf = 0; nf < 2; ++nf) {
      int n = nb*64 + wn + nf*16 + fr;
#pragma unroll
      for (int r = 0; r < 4; ++r) {
        int m = mb*128 + wm + mf*16 + fq*4 + r;
        dst[(size_t)m*256 + n] = acc[mf][nf][r];
      }
    }
}

// ------------------------------------------------------------------
// u = up[0]+up[1]+up[2]+up[3] + bias  (f32x4 over 18432x256)
__global__ __launch_bounds__(256) void reduce_u(
    const float* __restrict__ up, const float* __restrict__ b2, float* __restrict__ u)
{
  int i = blockIdx.x*256 + threadIdx.x;
  f32x4 a = *(const f32x4*)&up[(size_t)i*4];
  f32x4 b = *(const f32x4*)&up[4718592ull + (size_t)i*4];
  f32x4 c = *(const f32x4*)&up[9437184ull + (size_t)i*4];
  f32x4 d = *(const f32x4*)&up[14155776ull + (size_t)i*4];
  int n0 = (i*4) & 255;
  f32x4 o;
#pragma unroll
  for (int j = 0; j < 4; ++j) o[j] = (a[j] + b[j]) + (c[j] + d[j]) + b2[n0 + j];
  *(f32x4*)&u[(size_t)i*4] = o;
}

// ------------------------------------------------------------------
// Wsum[n*8+p][sd] = w[n, sd>>4, sd&15, p]   (9216 x 160 f32)
__global__ __launch_bounds__(192) void wsum_tr(const float* __restrict__ w,
    float* __restrict__ Ws)
{
  int n = blockIdx.x, t = threadIdx.x;
  __shared__ float wn[1280];
  for (int i = t; i < 1280; i += 192) wn[i] = w[n*1280 + i];
  __syncthreads();
  if (t < 160) {
#pragma unroll
    for (int p = 0; p < 8; ++p)
      Ws[((size_t)n*8 + p)*160 + t] = wn[(t>>4)*128 + (t&15)*8 + p];
  }
}

// ------------------------------------------------------------------
// s1 partials: part[ks][b][160] = u[b, k0:k0+288] @ Ws[k0:k0+288, :]
__global__ __launch_bounds__(192) void p1gemm(const float* __restrict__ u,
    const float* __restrict__ Ws, float* __restrict__ part)
{
  int b0 = blockIdx.x*32, k0 = blockIdx.y*288;
  int t = threadIdx.x;
  __shared__ float usm[288*36];
  for (int i = t; i < 288*32; i += 192) {
    int bl = i/288, kk = i - bl*288;
    usm[kk*36 + bl] = u[(size_t)(b0+bl)*9216 + k0 + kk];
  }
  __syncthreads();
  if (t < 160) {
    const float* wp = Ws + (size_t)k0*160 + t;
#pragma unroll 1
    for (int half = 0; half < 2; ++half) {
      float acc[16];
#pragma unroll
      for (int i = 0; i < 16; ++i) acc[i] = 0.f;
      for (int kk = 0; kk < 288; ++kk) {
        float wv = wp[(size_t)kk*160];
        const f32x4* ub = (const f32x4*)&usm[kk*36 + half*16];
        f32x4 u0 = ub[0], u1 = ub[1], u2 = ub[2], u3 = ub[3];
#pragma unroll
        for (int i = 0; i < 4; ++i) {
          acc[i]    += u0[i]*wv;
          acc[4+i]  += u1[i]*wv;
          acc[8+i]  += u2[i]*wv;
          acc[12+i] += u3[i]*wv;
        }
      }
      float* pp = &part[((size_t)blockIdx.y*512 + b0 + half*16)*160 + t];
#pragma unroll
      for (int i = 0; i < 16; ++i) pp[(size_t)i*160] = acc[i];
    }
  }
}

// ------------------------------------------------------------------
// v1 = squash(0.1 * sum_ks part[ks][b][:])
__global__ __launch_bounds__(192) void squash1(const float* __restrict__ part,
    float* __restrict__ vout)
{
  int b = blockIdx.x, t = threadIdx.x;
  if (t < 160) {
    float sv = 0.f;
    for (int ks = 0; ks < 32; ++ks) sv += part[((size_t)ks*512 + b)*160 + t];
    sv *= 0.1f;
    float n2 = sv*sv;
    n2 += __shfl_xor(n2, 1, 16);
    n2 += __shfl_xor(n2, 2, 16);
    n2 += __shfl_xor(n2, 4, 16);
    n2 += __shfl_xor(n2, 8, 16);
    float nrm = sqrtf(n2);
    float o = (n2/(1.f + n2)) * sv / (nrm + 1e-7f);
    vout[b*160 + t] = o;
  }
}

// ------------------------------------------------------------------
// u_hat -> uh[n][b][160] bf16 (n-major: stores fully coalesced).
__global__ __launch_bounds__(256) void uhat_kernel(
    const float* __restrict__ u, const float* __restrict__ w, USH* __restrict__ uh)
{
  int n = blockIdx.x, b0 = blockIdx.y*64;
  int t = threadIdx.x;
  __shared__ float wsm[20*65];
  __shared__ float usm[512];
  for (int i = t; i < 1280; i += 256) wsm[(i>>6)*65 + (i&63)] = w[n*1280 + i];
  for (int i = t; i < 512; i += 256) {
    int bl = i>>3, p = i&7;
    usm[i] = u[(size_t)(b0+bl)*9216 + n*8 + p];
  }
  __syncthreads();
  USH* dst = uh + ((size_t)n*512 + b0)*160;
  for (int v = t; v < 1280; v += 256) {
    int bl = v/20, oct = v - bl*20;
    const float* upt = &usm[bl*8];
    bf16x8 pk;
#pragma unroll
    for (int j = 0; j < 8; ++j) {
      const float* wp = &wsm[oct*65 + j*8];
      float a = 0.f;
#pragma unroll
      for (int p = 0; p < 8; ++p) a += wp[p]*upt[p];
      pk[j] = (short)f2bf(a);
    }
    *(bf16x8*)&dst[(size_t)v*8] = pk;
  }
}

// ------------------------------------------------------------------
// Routing pass partial, coalesced-b mapping: block = (16 b, 48 n),
// grid (32 bc, 24 nc) = 768 blocks (3/CU, 12 waves/CU). Thread (bL, s):
// per n the block's active lanes read uh[n][b0..b15][0..160] = ONE
// contiguous 5KB span; each thread owns (b,s,d) -> NO LDS, NO barrier.
// Softmax = width-16 shfl. 2-deep n-prefetch. partR = 24 chunks (7.9 MB;
// r17's 72 chunks cost ~47 MB of extra partial traffic per 2 passes).
// No L buffer: pass2 vin=v1; pass3 vin=v1+v2 (logits3 = uh.(v1+v2)).
__global__ __launch_bounds__(256) void route_part(
    const USH* __restrict__ uh, const float* __restrict__ vin,
    float* __restrict__ partR)
{
  int bc = blockIdx.x, nc = blockIdx.y;
  int b0 = bc*16, n0 = nc*48;
  int t = threadIdx.x;
  int bL = t >> 4, s = t & 15;
  bool act = s < 10;
  int b = b0 + bL;

  float vr[16];
#pragma unroll
  for (int d = 0; d < 16; ++d) vr[d] = 0.f;
  if (act) {
    const float* vp = vin + (size_t)b*160 + s*16;
#pragma unroll
    for (int d = 0; d < 16; ++d) vr[d] = vp[d];
  }
  float acc[16];
#pragma unroll
  for (int d = 0; d < 16; ++d) acc[d] = 0.f;

  const size_t nstride = (size_t)512*160;
  const USH* base = uh + ((size_t)n0*512 + b)*160 + s*16;

  bf16x8 c0{}, c1{};
  if (act) { c0 = *(const bf16x8*)base; c1 = *(const bf16x8*)(base + 8); }

  for (int ni = 0; ni < 48; ++ni) {
    bf16x8 f0 = c0, f1 = c1;
    if (ni + 1 < 48 && act) {
      const USH* p = base + (size_t)(ni+1)*nstride;
      f0 = *(const bf16x8*)p;
      f1 = *(const bf16x8*)(p + 8);
    }
    float uv[16];
    if (act) {
#pragma unroll
      for (int d = 0; d < 8; ++d) { uv[d] = bf2f((USH)c0[d]); uv[8+d] = bf2f((USH)c1[d]); }
    } else {
#pragma unroll
      for (int d = 0; d < 16; ++d) uv[d] = 0.f;
    }
    c0 = f0; c1 = f1;

    float dot = 0.f;
#pragma unroll
    for (int d = 0; d < 16; ++d) dot += uv[d]*vr[d];
    float lg = act ? dot : -1e30f;
    float mx = lg;
    mx = fmaxf(mx, __shfl_xor(mx, 1, 16));
    mx = fmaxf(mx, __shfl_xor(mx, 2, 16));
    mx = fmaxf(mx, __shfl_xor(mx, 4, 16));
    mx = fmaxf(mx, __shfl_xor(mx, 8, 16));
    float e = __expf(lg - mx);
    float sum = e;
    sum += __shfl_xor(sum, 1, 16);
    sum += __shfl_xor(sum, 2, 16);
    sum += __shfl_xor(sum, 4, 16);
    sum += __shfl_xor(sum, 8, 16);
    float c = e / sum;
#pragma unroll
    for (int d = 0; d < 16; ++d) acc[d] += c*uv[d];
  }

  if (act) {
    float* pp = &partR[((size_t)nc*512 + b)*160 + s*16];
#pragma unroll
    for (int q = 0; q < 4; ++q) {
      f32x4 o;
#pragma unroll
      for (int j = 0; j < 4; ++j) o[j] = acc[q*4 + j];
      *(f32x4*)(pp + q*4) = o;
    }
  }
}

// ------------------------------------------------------------------
// squash over 24 n-chunk partials.
// PASS2: vout=v2, vext=vprev+v2 (vsum). PASS3: vout=v3, vext=out.
template<int PASS>
__global__ __launch_bounds__(192) void squash_part(const float* __restrict__ partR,
    const float* __restrict__ vprev, float* __restrict__ vout, float* __restrict__ vext)
{
  int b = blockIdx.x, t = threadIdx.x;
  if (t < 160) {
    float sv = 0.f;
    for (int nc = 0; nc < 24; ++nc) sv += partR[((size_t)nc*512 + b)*160 + t];
    float n2 = sv*sv;
    n2 += __shfl_xor(n2, 1, 16);
    n2 += __shfl_xor(n2, 2, 16);
    n2 += __shfl_xor(n2, 4, 16);
    n2 += __shfl_xor(n2, 8, 16);
    float nrm = sqrtf(n2);
    float o = (n2/(1.f + n2)) * sv / (nrm + 1e-7f);
    vout[b*160 + t] = o;
    if (PASS == 2) vext[b*160 + t] = vprev[b*160 + t] + o;   // vsum = v1 + v2
    if (PASS == 3) vext[b*160 + t] = o;                       // out[0:81920] = v
  }
}

// ------------------------------------------------------------------
// decoder
__global__ __launch_bounds__(512) void d1_kernel(const float* __restrict__ v3,
    const int* __restrict__ labels, const float* __restrict__ w,
    const float* __restrict__ bias, float* __restrict__ r1)
{
  int b = blockIdx.x; int j = threadIdx.x;
  int lb = labels[b];
  float acc = bias[j];
#pragma unroll
  for (int d = 0; d < 16; ++d)
    acc += v3[b*160 + lb*16 + d] * w[(lb*16 + d)*512 + j];
  r1[(size_t)b*512 + j] = acc > 0.f ? acc : 0.f;
}

__global__ __launch_bounds__(256) void d2_kernel(const float* __restrict__ a,
    const float* __restrict__ w, const float* __restrict__ bias, float* __restrict__ o)
{
  int j = blockIdx.x*256 + threadIdx.x;
  int b0 = blockIdx.y*4;
  __shared__ float as[4*512];
  for (int i = threadIdx.x; i < 4*512; i += 256) as[i] = a[(size_t)(b0 + (i>>9))*512 + (i&511)];
  __syncthreads();
  float acc[4];
  float bs = bias[j];
#pragma unroll
  for (int i = 0; i < 4; ++i) acc[i] = bs;
  for (int k = 0; k < 512; ++k) {
    float wv = w[(size_t)k*1024 + j];
#pragma unroll
    for (int i = 0; i < 4; ++i) acc[i] += as[i*512 + k]*wv;
  }
#pragma unroll
  for (int i = 0; i < 4; ++i)
    o[(size_t)(b0+i)*1024 + j] = acc[i] > 0.f ? acc[i] : 0.f;
}

__global__ __launch_bounds__(256) void d3_kernel(const float* __restrict__ a,
    const float* __restrict__ w, const float* __restrict__ bias, float* __restrict__ o)
{
  int j = blockIdx.x*256 + threadIdx.x;
  int b0 = blockIdx.y*4;
  __shared__ float as[4*1024];
  for (int i = threadIdx.x; i < 4*1024; i += 256) as[i] = a[(size_t)(b0 + (i>>10))*1024 + (i&1023)];
  __syncthreads();
  if (j < 784) {
    float acc[4];
    float bs = bias[j];
#pragma unroll
    for (int i = 0; i < 4; ++i) acc[i] = bs;
    for (int k = 0; k < 1024; ++k) {
      float wv = w[(size_t)k*784 + j];
#pragma unroll
      for (int i = 0; i < 4; ++i) acc[i] += as[i*1024 + k]*wv;
    }
#pragma unroll
    for (int i = 0; i < 4; ++i)
      o[(size_t)(b0+i)*784 + j] = 1.f/(1.f + __expf(-acc[i]));
  }
}

// ------------------------------------------------------------------
extern "C" void kernel_launch(void* const* d_in, const int* in_sizes, int n_in,
                              void* d_out, int out_size, void* d_ws, size_t ws_size,
                              hipStream_t stream)
{
  const float* x   = (const float*)d_in[0];
  const int*   lab = (const int*)  d_in[1];
  const float* k1  = (const float*)d_in[2];
  const float* b1  = (const float*)d_in[3];
  const float* k2  = (const float*)d_in[4];
  const float* b2  = (const float*)d_in[5];
  const float* w   = (const float*)d_in[6];
  const float* d1w = (const float*)d_in[7];
  const float* d1b = (const float*)d_in[8];
  const float* d2w = (const float*)d_in[9];
  const float* d2b = (const float*)d_in[10];
  const float* d3w = (const float*)d_in[11];
  const float* d3b = (const float*)d_in[12];
  float* out = (float*)d_out;

  char* ws = (char*)d_ws;
  // layout (bytes) -- liveness audited:
  //   uh    [0, 188743680)          bf16 [1152][512][160]; live uhat->route3
  //   h     overlays [0, 104857600)   dead after conv2
  //   up    [104857600, 180355072)    dead after reduce_u
  //   xcol  [142606336, 181927936)    dead after gemm1
  //   u     [188743680, 207618048)    live conv2->uhat/p1gemm
  //   Wsum  [207618048, 213516288)    in dead-k2T region
  //   k2T   [207618048, 218234880)    dead after conv2
  //   part  [218234880, 228720640)    p1 partials; dead after squash1
  //   partR [218234880, 233963520)    route partials (24 chunks, 15.7MB max ok)
  //   k1T   [241827840, 241926144)
  //   v/r   beyond 242155520
  USH*   uh    = (USH*)(ws + 0);
  USH*   h     = (USH*)(ws + 0);
  float* up    = (float*)(ws + 104857600ull);
  USH*   xcol  = (USH*)(ws + 142606336ull);
  float* u     = (float*)(ws + 188743680ull);
  USH*   k2T   = (USH*)(ws + 207618048ull);
  float* Wsum  = (float*)(ws + 207618048ull);
  float* part  = (float*)(ws + 218234880ull);
  float* partR = (float*)(ws + 218234880ull);
  USH*   k1T   = (USH*)(ws + 241827840ull);
  float* v1    = (float*)(ws + 242155520ull);
  float* v2    = (float*)(ws + 242483200ull);
  float* v3    = (float*)(ws + 242810880ull);
  float* vsum  = (float*)(ws + 243138560ull);
  float* r1    = (float*)(ws + 243466240ull);
  float* r2    = (float*)(ws + 244514816ull);

  im2col_k<<<512, 256, 0, stream>>>(x, xcol);
  tr_k1<<<1, 256, 0, stream>>>(k1, k1T);
  gemm1<<<3200, 256, 0, stream>>>(xcol, k1T, b1, h);

  tr_k2<<<dim3(648,8), 256, 0, stream>>>(k2, k2T);
  conv2_mfma<<<2304, 256, 0, stream>>>(h, k2T, up);
  reduce_u<<<4608, 256, 0, stream>>>(up, b2, u);

  wsum_tr<<<1152, 192, 0, stream>>>(w, Wsum);
  p1gemm<<<dim3(16,32), 192, 0, stream>>>(u, Wsum, part);
  squash1<<<512, 192, 0, stream>>>(part, v1);

  uhat_kernel<<<dim3(1152,8), 256, 0, stream>>>(u, w, uh);

  route_part<<<dim3(32,24), 256, 0, stream>>>(uh, v1, partR);
  squash_part<2><<<512, 192, 0, stream>>>(partR, v1, v2, vsum);
  route_part<<<dim3(32,24), 256, 0, stream>>>(uh, vsum, partR);
  squash_part<3><<<512, 192, 0, stream>>>(partR, nullptr, v3, out);

  d1_kernel<<<512, 512, 0, stream>>>(v3, lab, d1w, d1b, r1);
  d2_kernel<<<dim3(4,128), 256, 0, stream>>>(r1, d2w, d2b, r2);
  d3_kernel<<<dim3(4,128), 256, 0, stream>>>(r2, d3w, d3b, out + 81920);
}

// Round 20
// 595.492 us; speedup vs baseline: 1.0570x; 1.0113x over previous
//
#include <hip/hip_runtime.h>

#define USH unsigned short

__device__ inline float bf2f(USH u){ return __uint_as_float(((unsigned)u)<<16); }
__device__ inline USH f2bf(float f){
  unsigned u = __float_as_uint(f);
  return (USH)((u + 0x7FFFu + ((u>>16)&1u))>>16);
}

typedef __attribute__((ext_vector_type(8))) short bf16x8;
typedef __attribute__((ext_vector_type(4))) float f32x4;

__device__ inline void gll16(const USH* g, USH* l){
  __builtin_amdgcn_global_load_lds((const __attribute__((address_space(1))) void*)g,
                                   (__attribute__((address_space(3))) void*)l, 16, 0, 0);
}

// ------------------------------------------------------------------
// im2col for conv1: x(512,28,28) f32 -> xcol[b*400 + y*20 + x][96] bf16
__global__ __launch_bounds__(256) void im2col_k(
    const float* __restrict__ x, USH* __restrict__ xcol)
{
  int b = blockIdx.x, t = threadIdx.x;
  __shared__ float xs[784];
  for (int i = t; i < 784; i += 256) xs[i] = x[b*784 + i];
  __syncthreads();
  USH* dst = xcol + (size_t)b*38400;
  for (int idx = t; idx < 38400; idx += 256) {
    int sp = idx / 96, k = idx - sp*96;
    int y = sp / 20, xx = sp - y*20;
    USH v = 0;
    if (k < 81) {
      int dy = k / 9, dx = k - dy*9;
      v = f2bf(xs[(y+dy)*28 + xx + dx]);
    }
    dst[idx] = v;
  }
}

// k1 (81,256) f32 -> k1T (256,96) bf16 zero-padded
__global__ __launch_bounds__(256) void tr_k1(const float* __restrict__ k1, USH* __restrict__ k1T)
{
  int n = threadIdx.x;
  for (int k = 0; k < 96; ++k)
    k1T[n*96 + k] = (k < 81) ? f2bf(k1[k*256 + n]) : (USH)0;
}

// ------------------------------------------------------------------
// conv1 as GEMM: C[204800 x 256] = xcol @ k1T^T, +bias, relu -> h bf16. No LDS.
__global__ __launch_bounds__(256) void gemm1(
    const USH* __restrict__ xcol, const USH* __restrict__ k1T,
    const float* __restrict__ b1, USH* __restrict__ h)
{
  int t = threadIdx.x;
  int m0 = blockIdx.x * 64;
  int lane = t & 63, wave = t >> 6;
  int wn = wave * 64;
  int fr = lane & 15, fq = lane >> 4;

  f32x4 acc[4][4];
#pragma unroll
  for (int i = 0; i < 4; ++i)
#pragma unroll
    for (int j = 0; j < 4; ++j)
#pragma unroll
      for (int r = 0; r < 4; ++r) acc[i][j][r] = 0.f;

#pragma unroll
  for (int kt = 0; kt < 3; ++kt) {
    int kc = kt*32 + fq*8;
    bf16x8 af[4], bg[4];
#pragma unroll
    for (int mf = 0; mf < 4; ++mf)
      af[mf] = *(const bf16x8*)&xcol[(size_t)(m0 + mf*16 + fr)*96 + kc];
#pragma unroll
    for (int nf = 0; nf < 4; ++nf)
      bg[nf] = *(const bf16x8*)&k1T[(size_t)(wn + nf*16 + fr)*96 + kc];
#pragma unroll
    for (int mf = 0; mf < 4; ++mf)
#pragma unroll
      for (int nf = 0; nf < 4; ++nf)
        acc[mf][nf] = __builtin_amdgcn_mfma_f32_16x16x32_bf16(af[mf], bg[nf], acc[mf][nf], 0,0,0);
  }

#pragma unroll
  for (int mf = 0; mf < 4; ++mf)
#pragma unroll
    for (int nf = 0; nf < 4; ++nf) {
      int n = wn + nf*16 + fr;
      float bias = b1[n];
#pragma unroll
      for (int r = 0; r < 4; ++r) {
        int m = m0 + mf*16 + fq*4 + r;
        float v = acc[mf][nf][r] + bias;
        h[(size_t)m*256 + n] = f2bf(v > 0.f ? v : 0.f);
      }
    }
}

// ------------------------------------------------------------------
// k2 (20736,256) f32 -> k2T (256,20736) bf16
__global__ __launch_bounds__(256) void tr_k2(const float* __restrict__ k2, USH* __restrict__ k2T)
{
  __shared__ float tile[32][33];
  int kb = blockIdx.x*32, nb = blockIdx.y*32;
  int tx = threadIdx.x & 31, ty = threadIdx.x >> 5;
#pragma unroll
  for (int r = 0; r < 4; ++r) {
    int k = kb + ty + r*8;
    tile[ty + r*8][tx] = k2[(size_t)k*256 + nb + tx];
  }
  __syncthreads();
#pragma unroll
  for (int r = 0; r < 4; ++r) {
    int n = nb + ty + r*8;
    k2T[(size_t)n*20736 + kb + tx] = f2bf(tile[tx][ty + r*8]);
  }
}

// ------------------------------------------------------------------
// Generic [K][N]-f32 -> [N][K]-bf16 transpose with N clamp (zero pad).
__global__ __launch_bounds__(256) void tr_dec(const float* __restrict__ in,
    USH* __restrict__ outT, int K, int N, int limN)
{
  __shared__ float tile[32][33];
  int kb = blockIdx.x*32, nb = blockIdx.y*32;
  int tx = threadIdx.x & 31, ty = threadIdx.x >> 5;
#pragma unroll
  for (int r = 0; r < 4; ++r) {
    int k = kb + ty + r*8;
    int n = nb + tx;
    tile[ty + r*8][tx] = (n < limN) ? in[(size_t)k*limN + n] : 0.f;
  }
  __syncthreads();
#pragma unroll
  for (int r = 0; r < 4; ++r) {
    int n = nb + ty + r*8;
    outT[(size_t)n*K + kb + tx] = f2bf(tile[tx][ty + r*8]);
  }
}

// ------------------------------------------------------------------
// conv2 implicit GEMM: bf16 MFMA 16x16x32, BM=128 BN=64 BK=64, 4 waves,
// 2-buffer LDS + XOR swizzle, split-K x4, XCD-aware 1D grid (r15-proven).
__global__ __launch_bounds__(256) void conv2_mfma(
    const USH* __restrict__ h, const USH* __restrict__ k2T,
    float* __restrict__ up)
{
  __shared__ __align__(16) USH Asm[2][128*64];
  __shared__ __align__(16) USH Bsm[2][64*64];
  int t = threadIdx.x;
  int flat = blockIdx.x;
  int xcd  = flat & 7;
  int slot = flat >> 3;
  int nb   = slot & 3;
  int rest = slot >> 2;
  int mb_l = rest % 18;
  int ksl  = rest / 18;
  int mb   = xcd*18 + mb_l;

  int sg = (((t&7) ^ ((t>>3)&7)) << 3);

  int arow_off[4];
#pragma unroll
  for (int i = 0; i < 4; ++i) {
    int row = (t>>3) + i*32;
    int m = mb*128 + row;
    int bb = m/36, r = m - bb*36;
    int oy = r/6, ox = r - oy*6;
    arow_off[i] = bb*102400 + oy*10240 + ox*512 + sg;
  }
  int brow_off[2];
#pragma unroll
  for (int i = 0; i < 2; ++i) {
    int nl = (t>>3) + i*32;
    brow_off[i] = (nb*64 + nl)*20736 + sg;
  }

  int lane = t & 63;
  int wave = t >> 6;
  int wm = (wave>>1)*64, wn = (wave&1)*32;
  int fr = lane & 15, fq = lane >> 4;

  f32x4 acc[4][2];
#pragma unroll
  for (int i = 0; i < 4; ++i)
#pragma unroll
    for (int j = 0; j < 2; ++j)
#pragma unroll
      for (int r = 0; r < 4; ++r) acc[i][j][r] = 0.f;

  int rg0 = (((0*4 + fq) ^ (fr&7)) << 3);
  int rg1 = (((1*4 + fq) ^ (fr&7)) << 3);

#define STAGE(buf, kt) do {                                            \
    int j_ = (kt) >> 2;                                                \
    int cin0_ = ((kt) & 3) << 6;                                       \
    int dy_ = j_/9, dx_ = j_ - dy_*9;                                  \
    int koff_ = (dy_*20 + dx_)*256 + cin0_;                            \
    USH* Ad_ = &Asm[buf][(t>>6)*512];                                  \
    USH* Bd_ = &Bsm[buf][(t>>6)*512];                                  \
    _Pragma("unroll")                                                  \
    for (int i_ = 0; i_ < 4; ++i_) gll16(h + arow_off[i_] + koff_, Ad_ + i_*2048); \
    _Pragma("unroll")                                                  \
    for (int i_ = 0; i_ < 2; ++i_) gll16(k2T + brow_off[i_] + (kt)*64, Bd_ + i_*2048); \
  } while(0)

  const int k0 = ksl*81, kend = k0 + 81;
  STAGE(0, k0);
  __syncthreads();

  int cur = 0;
  for (int kt = k0; kt < kend; ++kt) {
    if (kt + 1 < kend) STAGE(cur^1, kt+1);

    bf16x8 af[4][2], bg[2][2];
#pragma unroll
    for (int mf = 0; mf < 4; ++mf) {
      af[mf][0] = *(const bf16x8*)&Asm[cur][(wm + mf*16 + fr)*64 + rg0];
      af[mf][1] = *(const bf16x8*)&Asm[cur][(wm + mf*16 + fr)*64 + rg1];
    }
#pragma unroll
    for (int nf = 0; nf < 2; ++nf) {
      bg[nf][0] = *(const bf16x8*)&Bsm[cur][(wn + nf*16 + fr)*64 + rg0];
      bg[nf][1] = *(const bf16x8*)&Bsm[cur][(wn + nf*16 + fr)*64 + rg1];
    }
#pragma unroll
    for (int mf = 0; mf < 4; ++mf)
#pragma unroll
      for (int nf = 0; nf < 2; ++nf) {
        acc[mf][nf] = __builtin_amdgcn_mfma_f32_16x16x32_bf16(af[mf][0], bg[nf][0], acc[mf][nf], 0,0,0);
        acc[mf][nf] = __builtin_amdgcn_mfma_f32_16x16x32_bf16(af[mf][1], bg[nf][1], acc[mf][nf], 0,0,0);
      }
    __syncthreads();
    cur ^= 1;
  }
#undef STAGE

  float* dst = up + (size_t)ksl*4718592;
#pragma unroll
  for (int mf = 0; mf < 4; ++mf)
#pragma unroll
    for (int nf = 0; nf < 2; ++nf) {
      int n = nb*64 + wn + nf*16 + fr;
#pragma unroll
      for (int r = 0; r < 4; ++r) {
        int m = mb*128 + wm + mf*16 + fq*4 + r;
        dst[(size_t)m*256 + n] = acc[mf][nf][r];
      }
    }
}

// ------------------------------------------------------------------
// u = up[0]+up[1]+up[2]+up[3] + bias  (f32x4 over 18432x256)
__global__ __launch_bounds__(256) void reduce_u(
    const float* __restrict__ up, const float* __restrict__ b2, float* __restrict__ u)
{
  int i = blockIdx.x*256 + threadIdx.x;
  f32x4 a = *(const f32x4*)&up[(size_t)i*4];
  f32x4 b = *(const f32x4*)&up[4718592ull + (size_t)i*4];
  f32x4 c = *(const f32x4*)&up[9437184ull + (size_t)i*4];
  f32x4 d = *(const f32x4*)&up[14155776ull + (size_t)i*4];
  int n0 = (i*4) & 255;
  f32x4 o;
#pragma unroll
  for (int j = 0; j < 4; ++j) o[j] = (a[j] + b[j]) + (c[j] + d[j]) + b2[n0 + j];
  *(f32x4*)&u[(size_t)i*4] = o;
}

// ------------------------------------------------------------------
// Wsum[n*8+p][sd] = w[n, sd>>4, sd&15, p]   (9216 x 160 f32)
__global__ __launch_bounds__(192) void wsum_tr(const float* __restrict__ w,
    float* __restrict__ Ws)
{
  int n = blockIdx.x, t = threadIdx.x;
  __shared__ float wn[1280];
  for (int i = t; i < 1280; i += 192) wn[i] = w[n*1280 + i];
  __syncthreads();
  if (t < 160) {
#pragma unroll
    for (int p = 0; p < 8; ++p)
      Ws[((size_t)n*8 + p)*160 + t] = wn[(t>>4)*128 + (t&15)*8 + p];
  }
}

// ------------------------------------------------------------------
// s1 partials: part[ks][b][160] = u[b, k0:k0+288] @ Ws[k0:k0+288, :]
__global__ __launch_bounds__(192) void p1gemm(const float* __restrict__ u,
    const float* __restrict__ Ws, float* __restrict__ part)
{
  int b0 = blockIdx.x*32, k0 = blockIdx.y*288;
  int t = threadIdx.x;
  __shared__ float usm[288*36];
  for (int i = t; i < 288*32; i += 192) {
    int bl = i/288, kk = i - bl*288;
    usm[kk*36 + bl] = u[(size_t)(b0+bl)*9216 + k0 + kk];
  }
  __syncthreads();
  if (t < 160) {
    const float* wp = Ws + (size_t)k0*160 + t;
#pragma unroll 1
    for (int half = 0; half < 2; ++half) {
      float acc[16];
#pragma unroll
      for (int i = 0; i < 16; ++i) acc[i] = 0.f;
      for (int kk = 0; kk < 288; ++kk) {
        float wv = wp[(size_t)kk*160];
        const f32x4* ub = (const f32x4*)&usm[kk*36 + half*16];
        f32x4 u0 = ub[0], u1 = ub[1], u2 = ub[2], u3 = ub[3];
#pragma unroll
        for (int i = 0; i < 4; ++i) {
          acc[i]    += u0[i]*wv;
          acc[4+i]  += u1[i]*wv;
          acc[8+i]  += u2[i]*wv;
          acc[12+i] += u3[i]*wv;
        }
      }
      float* pp = &part[((size_t)blockIdx.y*512 + b0 + half*16)*160 + t];
#pragma unroll
      for (int i = 0; i < 16; ++i) pp[(size_t)i*160] = acc[i];
    }
  }
}

// ------------------------------------------------------------------
// v1 = squash(0.1 * sum_ks part[ks][b][:])
__global__ __launch_bounds__(192) void squash1(const float* __restrict__ part,
    float* __restrict__ vout)
{
  int b = blockIdx.x, t = threadIdx.x;
  if (t < 160) {
    float sv = 0.f;
    for (int ks = 0; ks < 32; ++ks) sv += part[((size_t)ks*512 + b)*160 + t];
    sv *= 0.1f;
    float n2 = sv*sv;
    n2 += __shfl_xor(n2, 1, 16);
    n2 += __shfl_xor(n2, 2, 16);
    n2 += __shfl_xor(n2, 4, 16);
    n2 += __shfl_xor(n2, 8, 16);
    float nrm = sqrtf(n2);
    float o = (n2/(1.f + n2)) * sv / (nrm + 1e-7f);
    vout[b*160 + t] = o;
  }
}

// ------------------------------------------------------------------
// u_hat -> uh[n][b][160] bf16 (n-major: stores fully coalesced).
__global__ __launch_bounds__(256) void uhat_kernel(
    const float* __restrict__ u, const float* __restrict__ w, USH* __restrict__ uh)
{
  int n = blockIdx.x, b0 = blockIdx.y*64;
  int t = threadIdx.x;
  __shared__ float wsm[20*65];
  __shared__ float usm[512];
  for (int i = t; i < 1280; i += 256) wsm[(i>>6)*65 + (i&63)] = w[n*1280 + i];
  for (int i = t; i < 512; i += 256) {
    int bl = i>>3, p = i&7;
    usm[i] = u[(size_t)(b0+bl)*9216 + n*8 + p];
  }
  __syncthreads();
  USH* dst = uh + ((size_t)n*512 + b0)*160;
  for (int v = t; v < 1280; v += 256) {
    int bl = v/20, oct = v - bl*20;
    const float* upt = &usm[bl*8];
    bf16x8 pk;
#pragma unroll
    for (int j = 0; j < 8; ++j) {
      const float* wp = &wsm[oct*65 + j*8];
      float a = 0.f;
#pragma unroll
      for (int p = 0; p < 8; ++p) a += wp[p]*upt[p];
      pk[j] = (short)f2bf(a);
    }
    *(bf16x8*)&dst[(size_t)v*8] = pk;
  }
}

// ------------------------------------------------------------------
// Routing pass partial, coalesced-b mapping (r18-proven) + 3-deep prefetch.
// Block = (16 b, 48 n), grid (32, 24). No LDS, no barriers.
__global__ __launch_bounds__(256) void route_part(
    const USH* __restrict__ uh, const float* __restrict__ vin,
    float* __restrict__ partR)
{
  int bc = blockIdx.x, nc = blockIdx.y;
  int b0 = bc*16, n0 = nc*48;
  int t = threadIdx.x;
  int bL = t >> 4, s = t & 15;
  bool act = s < 10;
  int b = b0 + bL;

  float vr[16];
#pragma unroll
  for (int d = 0; d < 16; ++d) vr[d] = 0.f;
  if (act) {
    const float* vp = vin + (size_t)b*160 + s*16;
#pragma unroll
    for (int d = 0; d < 16; ++d) vr[d] = vp[d];
  }
  float acc[16];
#pragma unroll
  for (int d = 0; d < 16; ++d) acc[d] = 0.f;

  const size_t nstride = (size_t)512*160;
  const USH* base = uh + ((size_t)n0*512 + b)*160 + s*16;

  bf16x8 c0{}, c1{}, p0{}, p1{};
  if (act) {
    c0 = *(const bf16x8*)base;              c1 = *(const bf16x8*)(base + 8);
    p0 = *(const bf16x8*)(base + nstride);  p1 = *(const bf16x8*)(base + nstride + 8);
  }

  for (int ni = 0; ni < 48; ++ni) {
    bf16x8 f0 = p0, f1 = p1;
    if (ni + 2 < 48 && act) {
      const USH* p = base + (size_t)(ni+2)*nstride;
      f0 = *(const bf16x8*)p;
      f1 = *(const bf16x8*)(p + 8);
    }
    float uv[16];
    if (act) {
#pragma unroll
      for (int d = 0; d < 8; ++d) { uv[d] = bf2f((USH)c0[d]); uv[8+d] = bf2f((USH)c1[d]); }
    } else {
#pragma unroll
      for (int d = 0; d < 16; ++d) uv[d] = 0.f;
    }
    c0 = p0; c1 = p1;
    p0 = f0; p1 = f1;

    float dot = 0.f;
#pragma unroll
    for (int d = 0; d < 16; ++d) dot += uv[d]*vr[d];
    float lg = act ? dot : -1e30f;
    float mx = lg;
    mx = fmaxf(mx, __shfl_xor(mx, 1, 16));
    mx = fmaxf(mx, __shfl_xor(mx, 2, 16));
    mx = fmaxf(mx, __shfl_xor(mx, 4, 16));
    mx = fmaxf(mx, __shfl_xor(mx, 8, 16));
    float e = __expf(lg - mx);
    float sum = e;
    sum += __shfl_xor(sum, 1, 16);
    sum += __shfl_xor(sum, 2, 16);
    sum += __shfl_xor(sum, 4, 16);
    sum += __shfl_xor(sum, 8, 16);
    float c = e / sum;
#pragma unroll
    for (int d = 0; d < 16; ++d) acc[d] += c*uv[d];
  }

  if (act) {
    float* pp = &partR[((size_t)nc*512 + b)*160 + s*16];
#pragma unroll
    for (int q = 0; q < 4; ++q) {
      f32x4 o;
#pragma unroll
      for (int j = 0; j < 4; ++j) o[j] = acc[q*4 + j];
      *(f32x4*)(pp + q*4) = o;
    }
  }
}

// ------------------------------------------------------------------
// squash over 24 n-chunk partials.
// PASS2: vout=v2, vext=vprev+v2 (vsum). PASS3: vout=v3, vext=out.
template<int PASS>
__global__ __launch_bounds__(192) void squash_part(const float* __restrict__ partR,
    const float* __restrict__ vprev, float* __restrict__ vout, float* __restrict__ vext)
{
  int b = blockIdx.x, t = threadIdx.x;
  if (t < 160) {
    float sv = 0.f;
    for (int nc = 0; nc < 24; ++nc) sv += partR[((size_t)nc*512 + b)*160 + t];
    float n2 = sv*sv;
    n2 += __shfl_xor(n2, 1, 16);
    n2 += __shfl_xor(n2, 2, 16);
    n2 += __shfl_xor(n2, 4, 16);
    n2 += __shfl_xor(n2, 8, 16);
    float nrm = sqrtf(n2);
    float o = (n2/(1.f + n2)) * sv / (nrm + 1e-7f);
    vout[b*160 + t] = o;
    if (PASS == 2) vext[b*160 + t] = vprev[b*160 + t] + o;   // vsum = v1 + v2
    if (PASS == 3) vext[b*160 + t] = o;                       // out[0:81920] = v
  }
}

// ------------------------------------------------------------------
// decoder: d1 (tiny, one-hot mask -> K=16) writes bf16 activations
__global__ __launch_bounds__(512) void d1_kernel(const float* __restrict__ v3,
    const int* __restrict__ labels, const float* __restrict__ w,
    const float* __restrict__ bias, USH* __restrict__ r1b)
{
  int b = blockIdx.x; int j = threadIdx.x;
  int lb = labels[b];
  float acc = bias[j];
#pragma unroll
  for (int d = 0; d < 16; ++d)
    acc += v3[b*160 + lb*16 + d] * w[(lb*16 + d)*512 + j];
  r1b[(size_t)b*512 + j] = f2bf(acc > 0.f ? acc : 0.f);
}

// ------------------------------------------------------------------
// decoder GEMM via MFMA (gemm1 pattern): C[512 x N] = A[512 x K] @ Bt^T.
// MODE 0: +bias, relu -> bf16 (d2).  MODE 1: +bias, sigmoid -> f32 out,
// store guarded n < limN (d3; Bt zero-padded to N rows).
template<int MODE>
__global__ __launch_bounds__(256) void gemm_dec(
    const USH* __restrict__ A, const USH* __restrict__ Bt,
    const float* __restrict__ bias, void* __restrict__ Cv,
    int K, int limN)
{
  int t = threadIdx.x;
  int m0 = blockIdx.x * 64;
  int n0 = blockIdx.y * 256;
  int lane = t & 63, wave = t >> 6;
  int wn = n0 + wave * 64;
  int fr = lane & 15, fq = lane >> 4;

  f32x4 acc[4][4];
#pragma unroll
  for (int i = 0; i < 4; ++i)
#pragma unroll
    for (int j = 0; j < 4; ++j)
#pragma unroll
      for (int r = 0; r < 4; ++r) acc[i][j][r] = 0.f;

  for (int kt = 0; kt < K/32; ++kt) {
    int kc = kt*32 + fq*8;
    bf16x8 af[4], bg[4];
#pragma unroll
    for (int mf = 0; mf < 4; ++mf)
      af[mf] = *(const bf16x8*)&A[(size_t)(m0 + mf*16 + fr)*K + kc];
#pragma unroll
    for (int nf = 0; nf < 4; ++nf)
      bg[nf] = *(const bf16x8*)&Bt[(size_t)(wn + nf*16 + fr)*K + kc];
#pragma unroll
    for (int mf = 0; mf < 4; ++mf)
#pragma unroll
      for (int nf = 0; nf < 4; ++nf)
        acc[mf][nf] = __builtin_amdgcn_mfma_f32_16x16x32_bf16(af[mf], bg[nf], acc[mf][nf], 0,0,0);
  }

#pragma unroll
  for (int mf = 0; mf < 4; ++mf)
#pragma unroll
    for (int nf = 0; nf < 4; ++nf) {
      int n = wn + nf*16 + fr;
      float bs = (n < limN) ? bias[n] : 0.f;
#pragma unroll
      for (int r = 0; r < 4; ++r) {
        int m = m0 + mf*16 + fq*4 + r;
        float v = acc[mf][nf][r] + bs;
        if (MODE == 0) {
          ((USH*)Cv)[(size_t)m*limN + n] = f2bf(v > 0.f ? v : 0.f);
        } else {
          if (n < limN)
            ((float*)Cv)[(size_t)m*limN + n] = 1.f/(1.f + __expf(-v));
        }
      }
    }
}

// ------------------------------------------------------------------
extern "C" void kernel_launch(void* const* d_in, const int* in_sizes, int n_in,
                              void* d_out, int out_size, void* d_ws, size_t ws_size,
                              hipStream_t stream)
{
  const float* x   = (const float*)d_in[0];
  const int*   lab = (const int*)  d_in[1];
  const float* k1  = (const float*)d_in[2];
  const float* b1  = (const float*)d_in[3];
  const float* k2  = (const float*)d_in[4];
  const float* b2  = (const float*)d_in[5];
  const float* w   = (const float*)d_in[6];
  const float* d1w = (const float*)d_in[7];
  const float* d1b = (const float*)d_in[8];
  const float* d2w = (const float*)d_in[9];
  const float* d2b = (const float*)d_in[10];
  const float* d3w = (const float*)d_in[11];
  const float* d3b = (const float*)d_in[12];
  float* out = (float*)d_out;

  char* ws = (char*)d_ws;
  // layout (bytes) -- liveness audited (r19 bug: decoder buffers had been
  // placed INSIDE the live uh range [0,188743680); now in the free gap
  // after partR and before k1T):
  //   uh    [0, 188743680)          bf16 [1152][512][160]; live uhat->route3
  //   h     overlays [0, 104857600)   dead after conv2 (before uhat)
  //   up    [104857600, 180355072)    dead after reduce_u (before uhat)
  //   xcol  [142606336, 181927936)    dead after gemm1 (before conv2)
  //   u     [188743680, 207618048)    live conv2->uhat/p1gemm
  //   Wsum  [207618048, 213516288)    in dead-k2T region
  //   k2T   [207618048, 218234880)    dead after conv2
  //   part  [218234880, 228720640)    p1 partials; dead after squash1
  //   partR [218234880, 233963520)    route partials (24 chunks)
  //   d2wT  [233963520, 235012096)    1 MB  bf16 [1024][512]
  //   d3wT  [235012096, 237109248)    2 MB  bf16 [1024][1024] zero-padded
  //   r1b   [237109248, 237633536)    bf16 [512][512]
  //   r2b   [237633536, 238682112)    bf16 [512][1024]   (< k1T at 241827840)
  //   k1T   [241827840, 241926144)
  //   v/r   beyond 242155520
  USH*   uh    = (USH*)(ws + 0);
  USH*   h     = (USH*)(ws + 0);
  float* up    = (float*)(ws + 104857600ull);
  USH*   xcol  = (USH*)(ws + 142606336ull);
  float* u     = (float*)(ws + 188743680ull);
  USH*   k2T   = (USH*)(ws + 207618048ull);
  float* Wsum  = (float*)(ws + 207618048ull);
  float* part  = (float*)(ws + 218234880ull);
  float* partR = (float*)(ws + 218234880ull);
  USH*   d2wT  = (USH*)(ws + 233963520ull);
  USH*   d3wT  = (USH*)(ws + 235012096ull);
  USH*   r1b   = (USH*)(ws + 237109248ull);
  USH*   r2b   = (USH*)(ws + 237633536ull);
  USH*   k1T   = (USH*)(ws + 241827840ull);
  float* v1    = (float*)(ws + 242155520ull);
  float* v2    = (float*)(ws + 242483200ull);
  float* v3    = (float*)(ws + 242810880ull);
  float* vsum  = (float*)(ws + 243138560ull);

  im2col_k<<<512, 256, 0, stream>>>(x, xcol);
  tr_k1<<<1, 256, 0, stream>>>(k1, k1T);
  gemm1<<<3200, 256, 0, stream>>>(xcol, k1T, b1, h);

  tr_k2<<<dim3(648,8), 256, 0, stream>>>(k2, k2T);
  conv2_mfma<<<2304, 256, 0, stream>>>(h, k2T, up);
  reduce_u<<<4608, 256, 0, stream>>>(up, b2, u);

  wsum_tr<<<1152, 192, 0, stream>>>(w, Wsum);
  p1gemm<<<dim3(16,32), 192, 0, stream>>>(u, Wsum, part);
  squash1<<<512, 192, 0, stream>>>(part, v1);

  uhat_kernel<<<dim3(1152,8), 256, 0, stream>>>(u, w, uh);

  // decoder weight transposes (region disjoint from uh/partR)
  tr_dec<<<dim3(16,32), 256, 0, stream>>>(d2w, d2wT, 512, 1024, 1024);
  tr_dec<<<dim3(32,32), 256, 0, stream>>>(d3w, d3wT, 1024, 1024, 784);

  route_part<<<dim3(32,24), 256, 0, stream>>>(uh, v1, partR);
  squash_part<2><<<512, 192, 0, stream>>>(partR, v1, v2, vsum);
  route_part<<<dim3(32,24), 256, 0, stream>>>(uh, vsum, partR);
  squash_part<3><<<512, 192, 0, stream>>>(partR, nullptr, v3, out);

  d1_kernel<<<512, 512, 0, stream>>>(v3, lab, d1w, d1b, r1b);
  gemm_dec<0><<<dim3(8,4), 256, 0, stream>>>(r1b, d2wT, d2b, r2b, 512, 1024);
  gemm_dec<1><<<dim3(8,4), 256, 0, stream>>>(r2b, d3wT, d3b, out + 81920, 1024, 784);
}